// Round 2
// baseline (261.880 us; speedup 1.0000x reference)
//
#include <hip/hip_runtime.h>
#include <stdint.h>
#include <stddef.h>
#include <math.h>

#define E_ 32
#define H_ 128
#define V_ 32000
#define NB 32
#define NT 128

typedef float f32x4 __attribute__((ext_vector_type(4)));
typedef short s16x8 __attribute__((ext_vector_type(8)));
typedef unsigned short u16x4 __attribute__((ext_vector_type(4)));

__device__ inline unsigned short f2bf(float f) {
  uint32_t u = __float_as_uint(f);
  return (unsigned short)((u + 0x7FFFu + ((u >> 16) & 1u)) >> 16);
}
// Precise activations: OCML expf/tanhf (~1-2 ulp, no cancellation).
// The LSTM recurrence amplifies per-step noise ~1e4x over 128 steps, so the
// fast __expf-based (1-t)/(1+t) tanh (5e-4 rel err near 0) broke tolerance.
__device__ inline float sigmoid_(float x) { return 1.f / (1.f + expf(-x)); }
__device__ inline float tanh_(float x) { return tanhf(x); }

// ---------------------------------------------------------------------------
// Kernel A: blocks 0..31  -> per-batch LSTM recurrence (fp32, U rows in VGPRs)
//           blocks 32..255 -> convert Vw fp32 -> bf16 (runs on idle CUs)
// ---------------------------------------------------------------------------
__global__ __launch_bounds__(512, 2)
void lstm_rec(const float* __restrict__ x,
              const float* __restrict__ Wf, const float* __restrict__ bWf,
              const float* __restrict__ Uf, const float* __restrict__ bUf,
              const float* __restrict__ Wi, const float* __restrict__ bWi,
              const float* __restrict__ Ui, const float* __restrict__ bUi,
              const float* __restrict__ Wc, const float* __restrict__ bWc,
              const float* __restrict__ Uc, const float* __restrict__ bUc,
              const float* __restrict__ Wo, const float* __restrict__ bWo,
              const float* __restrict__ Uo, const float* __restrict__ bUo,
              const float* __restrict__ Vw,
              unsigned short* __restrict__ hbf,   // [NB*NT, H_] bf16 bits
              unsigned short* __restrict__ vwbf,  // [V_*H_] bf16 bits
              float* __restrict__ hlast)          // d_out tail [NB, H_]
{
  const int bid = blockIdx.x;
  const int tid = threadIdx.x;

  if (bid >= NB) {
    // -------- Vw fp32 -> bf16 conversion --------
    const int n4 = V_ * H_ / 4;  // 1,024,000 float4 groups
    for (int i = (bid - NB) * 512 + tid; i < n4; i += (256 - NB) * 512) {
      f32x4 v = *reinterpret_cast<const f32x4*>(Vw + (size_t)i * 4);
      u16x4 o;
      o.x = f2bf(v.x); o.y = f2bf(v.y); o.z = f2bf(v.z); o.w = f2bf(v.w);
      *reinterpret_cast<u16x4*>(vwbf + (size_t)i * 4) = o;
    }
    return;
  }

  // -------- recurrence for batch element `bid` --------
  __shared__ __align__(16) float xs[NT * E_];  // 16 KB: x[bid] time-major rows
  __shared__ __align__(16) float hs[H_];       // current hidden state
  __shared__ __align__(16) float gl[4][H_];    // gate values f,i,ctil,o

  const int g = tid >> 7;    // 0:f 1:i 2:ctil 3:o
  const int j = tid & 127;   // output index within H

  const float *Wg, *Ug, *bWg, *bUg;
  if      (g == 0) { Wg = Wf; Ug = Uf; bWg = bWf; bUg = bUf; }
  else if (g == 1) { Wg = Wi; Ug = Ui; bWg = bWi; bUg = bUi; }
  else if (g == 2) { Wg = Wc; Ug = Uc; bWg = bWc; bUg = bUc; }
  else             { Wg = Wo; Ug = Uo; bWg = bWo; bUg = bUo; }

  // Pin weight rows in VGPRs: W row (8 x f32x4), U row (32 x f32x4)
  f32x4 wreg[8];
  f32x4 ureg[32];
  {
    const f32x4* Wp = reinterpret_cast<const f32x4*>(Wg + j * E_);
    const f32x4* Up = reinterpret_cast<const f32x4*>(Ug + j * H_);
#pragma unroll
    for (int q = 0; q < 8; ++q) wreg[q] = Wp[q];
#pragma unroll
    for (int q = 0; q < 32; ++q) ureg[q] = Up[q];
  }
  const float bias = bWg[j] + bUg[j];  // fold both biases

  // preload x[bid] into LDS
  for (int i = tid; i < NT * E_; i += 512) xs[i] = x[bid * (NT * E_) + i];
  if (tid < H_) hs[tid] = 0.f;
  float creg = 0.f;  // cell state, owned by threads tid<128 (g==0)
  __syncthreads();

  for (int t = 0; t < NT; ++t) {
    f32x4 a0 = {0.f, 0.f, 0.f, 0.f};
    f32x4 a1 = {0.f, 0.f, 0.f, 0.f};
    const f32x4* xv = reinterpret_cast<const f32x4*>(xs + t * E_);
#pragma unroll
    for (int q = 0; q < 8; ++q) {
      if (q & 1) a1 += wreg[q] * xv[q]; else a0 += wreg[q] * xv[q];
    }
    const f32x4* hv = reinterpret_cast<const f32x4*>(hs);
#pragma unroll
    for (int q = 0; q < 32; ++q) {
      if (q & 1) a1 += ureg[q] * hv[q]; else a0 += ureg[q] * hv[q];
    }
    f32x4 s4 = a0 + a1;
    float acc = bias + s4.x + s4.y + s4.z + s4.w;

    float val = (g == 2) ? tanh_(acc) : sigmoid_(acc);
    gl[g][j] = val;
    __syncthreads();

    if (tid < H_) {
      float f_ = gl[0][tid], i_ = gl[1][tid], ct = gl[2][tid], o_ = gl[3][tid];
      float cn = f_ * creg + i_ * ct;
      creg = cn;
      float hn = o_ * tanh_(cn);
      hs[tid] = hn;
      hbf[((size_t)bid * NT + t) * H_ + tid] = f2bf(hn);
      if (t == NT - 1) hlast[bid * H_ + tid] = hn;
    }
    __syncthreads();
  }
}

// ---------------------------------------------------------------------------
// Kernel B: out[4096, 32000] = hbf @ vwbf^T + Vb   (bf16 MFMA, K=128 one pass)
// 128x128 tile per 256-thread WG; 4 waves in 2x2, each wave 64x64.
// LDS tiles XOR-swizzled: element [row][colbyte] at row*256 + (colbyte ^ ((row&7)<<4))
// ---------------------------------------------------------------------------
__global__ __launch_bounds__(256, 2)
void vocab_gemm(const unsigned short* __restrict__ hbf,
                const unsigned short* __restrict__ vwbf,
                const float* __restrict__ Vb,
                float* __restrict__ out)
{
  __shared__ __align__(16) unsigned char As[128 * 256];  // 32 KB
  __shared__ __align__(16) unsigned char Bs[128 * 256];  // 32 KB

  const int tid = threadIdx.x;
  const int ntile = blockIdx.x;  // 0..249
  const int mtile = blockIdx.y;  // 0..31

  const unsigned char* Ag = reinterpret_cast<const unsigned char*>(hbf) + (size_t)mtile * 128 * 256;
  const unsigned char* Bg = reinterpret_cast<const unsigned char*>(vwbf) + (size_t)ntile * 128 * 256;

  // Stage with swizzle: LDS linear L receives global byte row*256 + ((L&255)^sw)
#pragma unroll
  for (int it = 0; it < 8; ++it) {
    int L = it * 4096 + tid * 16;
    int row = L >> 8;
    int sw = (row & 7) << 4;
    int src = (L & ~255) | ((L & 255) ^ sw);
    *reinterpret_cast<f32x4*>(&As[L]) = *reinterpret_cast<const f32x4*>(Ag + src);
    *reinterpret_cast<f32x4*>(&Bs[L]) = *reinterpret_cast<const f32x4*>(Bg + src);
  }
  __syncthreads();

  const int lane = tid & 63;
  const int w = tid >> 6;
  const int wr = w >> 1, wc = w & 1;
  const int l15 = lane & 15, lh = lane >> 4;

  f32x4 acc[4][4];
#pragma unroll
  for (int mt = 0; mt < 4; ++mt)
#pragma unroll
    for (int nt = 0; nt < 4; ++nt)
      acc[mt][nt] = (f32x4){0.f, 0.f, 0.f, 0.f};

#pragma unroll
  for (int kt = 0; kt < 4; ++kt) {
    const int cb = kt * 64 + lh * 16;  // k-byte offset of this lane's 8 bf16
    s16x8 af[4], bfr[4];
#pragma unroll
    for (int mt = 0; mt < 4; ++mt) {
      int ra = wr * 64 + mt * 16 + l15;
      af[mt] = *reinterpret_cast<const s16x8*>(&As[ra * 256 + (cb ^ ((ra & 7) << 4))]);
      int rb = wc * 64 + mt * 16 + l15;
      bfr[mt] = *reinterpret_cast<const s16x8*>(&Bs[rb * 256 + (cb ^ ((rb & 7) << 4))]);
    }
#pragma unroll
    for (int mt = 0; mt < 4; ++mt)
#pragma unroll
      for (int nt = 0; nt < 4; ++nt)
        acc[mt][nt] = __builtin_amdgcn_mfma_f32_16x16x32_bf16(af[mt], bfr[nt], acc[mt][nt], 0, 0, 0);
  }

  float vb[4];
#pragma unroll
  for (int nt = 0; nt < 4; ++nt)
    vb[nt] = Vb[ntile * 128 + wc * 64 + nt * 16 + l15];

#pragma unroll
  for (int mt = 0; mt < 4; ++mt) {
#pragma unroll
    for (int i = 0; i < 4; ++i) {
      int rrow = mtile * 128 + wr * 64 + mt * 16 + lh * 4 + i;
      float* orow = out + (size_t)rrow * V_ + ntile * 128 + wc * 64;
#pragma unroll
      for (int nt = 0; nt < 4; ++nt)
        orow[nt * 16 + l15] = acc[mt][nt][i] + vb[nt];
    }
  }
}

// ---------------------------------------------------------------------------
extern "C" void kernel_launch(void* const* d_in, const int* in_sizes, int n_in,
                              void* d_out, int out_size, void* d_ws, size_t ws_size,
                              hipStream_t stream) {
  const float* x   = (const float*)d_in[0];
  const float* Wf  = (const float*)d_in[1];
  const float* bWf = (const float*)d_in[2];
  const float* Uf  = (const float*)d_in[3];
  const float* bUf = (const float*)d_in[4];
  const float* Wi  = (const float*)d_in[5];
  const float* bWi = (const float*)d_in[6];
  const float* Ui  = (const float*)d_in[7];
  const float* bUi = (const float*)d_in[8];
  const float* Wc  = (const float*)d_in[9];
  const float* bWc = (const float*)d_in[10];
  const float* Uc  = (const float*)d_in[11];
  const float* bUc = (const float*)d_in[12];
  const float* Wo  = (const float*)d_in[13];
  const float* bWo = (const float*)d_in[14];
  const float* Uo  = (const float*)d_in[15];
  const float* bUo = (const float*)d_in[16];
  const float* Vw  = (const float*)d_in[17];
  const float* Vb  = (const float*)d_in[18];
  float* out = (float*)d_out;

  unsigned short* hbf  = (unsigned short*)d_ws;                       // 1 MB
  unsigned short* vwbf = (unsigned short*)((char*)d_ws + (1u << 20)); // 8.2 MB
  float* hlast = out + (size_t)NB * NT * V_;

  hipLaunchKernelGGL(lstm_rec, dim3(256), dim3(512), 0, stream,
                     x, Wf, bWf, Uf, bUf, Wi, bWi, Ui, bUi, Wc, bWc, Uc, bUc,
                     Wo, bWo, Uo, bUo, Vw, hbf, vwbf, hlast);
  hipLaunchKernelGGL(vocab_gemm, dim3(V_ / 128, (NB * NT) / 128), dim3(256), 0, stream,
                     hbf, vwbf, Vb, out);
}